// Round 11
// baseline (223.478 us; speedup 1.0000x reference)
//
#include <hip/hip_runtime.h>

// Attention_29231547416680: B=4, N=2048, CH=512, H=8, D=64, fp32 in/out.
// R11 = R10 with proj fixed: explicit 1-deep register prefetch (two named
//       fragment sets, manual unroll-by-2) so L2 latency hides under MFMAs.
//       attn (single-bf16 PV, 48KB dbuf) and prep unchanged from R10.

typedef float f32x4 __attribute__((ext_vector_type(4)));
typedef float f32x16 __attribute__((ext_vector_type(16)));
typedef short short8 __attribute__((ext_vector_type(8)));

#define MFMA16(a, b, c) __builtin_amdgcn_mfma_f32_16x16x32_bf16((a), (b), (c), 0, 0, 0)
#define MFMA32(a, b, c) __builtin_amdgcn_mfma_f32_32x32x16_bf16((a), (b), (c), 0, 0, 0)

#if __has_builtin(__builtin_amdgcn_exp2f)
#define EXP2(x) __builtin_amdgcn_exp2f(x)
#else
#define EXP2(x) exp2f(x)
#endif

#define NBH 32
#define NSEQ 2048
#define DH 64

__device__ __forceinline__ unsigned short f2bf(float f) {
  unsigned int u = __float_as_uint(f);
  u += 0x7fffu + ((u >> 16) & 1u);  // RTNE
  return (unsigned short)(u >> 16);
}
__device__ __forceinline__ float bf2f(unsigned short h) {
  return __uint_as_float(((unsigned int)h) << 16);
}
__device__ __forceinline__ void split_bf16(float f, unsigned short& hi, unsigned short& lo) {
  hi = f2bf(f);
  lo = f2bf(f - bf2f(hi));
}

__device__ __forceinline__ unsigned cvtpk_bf16(float a, float b) {
  unsigned d;
  asm("v_cvt_pk_bf16_f32 %0, %1, %2" : "=v"(d) : "v"(a), "v"(b));
  return d;
}
__device__ __forceinline__ void permswap(unsigned& a, unsigned& b) {
  asm("v_permlane32_swap_b32 %0, %1" : "+v"(a), "+v"(b));
}
// lo = (ce.row0 | co.row0), hi = (ce.row1 | co.row1); S2 selects HW direction.
template <bool S2>
__device__ __forceinline__ void xsw(unsigned ce, unsigned co, unsigned& lo, unsigned& hi) {
  if (S2) { permswap(ce, co); }
  else    { permswap(co, ce); }
  lo = ce;
  hi = co;
}

// ---------------- prep: mask bit-pack + x/W hi-lo split (R10 verbatim) ----------------
__global__ __launch_bounds__(256) void prep_kernel(
    const void* __restrict__ mraw, unsigned long long* __restrict__ Mp,
    const float* __restrict__ x,
    const float* __restrict__ Wq, const float* __restrict__ Wk, const float* __restrict__ Wv,
    unsigned short* __restrict__ xh, unsigned short* __restrict__ xl,
    unsigned short* __restrict__ wh, unsigned short* __restrict__ wl) {
  const int tid = threadIdx.x;
  __shared__ int s_bad;
  if (tid == 0) s_bad = 0;
  __syncthreads();
  const unsigned int* mw32 = (const unsigned int*)mraw;
  {
    unsigned int w0 = mw32[tid], w1 = mw32[256 + tid];
    bool ok = (w0 == 0u || w0 == 1u || w0 == 0x3f800000u) &&
              (w1 == 0u || w1 == 1u || w1 == 0x3f800000u);
    if (!ok) s_bad = 1;
  }
  __syncthreads();
  const size_t e0 = (size_t)blockIdx.x * 16384 + (size_t)tid * 64;
  unsigned long long bits = 0ull;
  if (s_bad == 0) {
    const uint4* p = (const uint4*)mw32 + (e0 >> 2);
#pragma unroll
    for (int j = 0; j < 16; ++j) {
      uint4 v = p[j];
      unsigned nib = (v.x != 0u) | ((v.y != 0u) << 1) | ((v.z != 0u) << 2) | ((v.w != 0u) << 3);
      bits |= (unsigned long long)nib << (j * 4);
    }
  } else {
    const uint4* p = (const uint4*)((const unsigned char*)mraw + e0);
#pragma unroll
    for (int j = 0; j < 4; ++j) {
      uint4 v = p[j];
      unsigned dw[4] = {v.x, v.y, v.z, v.w};
#pragma unroll
      for (int d = 0; d < 4; ++d) {
        unsigned nib = (((dw[d]) & 0xffu) != 0u) | ((((dw[d] >> 8) & 0xffu) != 0u) << 1) |
                       ((((dw[d] >> 16) & 0xffu) != 0u) << 2) | ((((dw[d] >> 24) & 0xffu) != 0u) << 3);
        bits |= (unsigned long long)nib << ((j * 4 + d) * 4);
      }
    }
  }
  Mp[e0 >> 6] = bits;

  const int gtid = blockIdx.x * 256 + tid;
  const float4* x4 = (const float4*)x;
#pragma unroll
  for (int rep = 0; rep < 4; ++rep) {
    int i = gtid + rep * 262144;
    float4 v = x4[i];
    unsigned short h0, l0, h1, l1, h2, l2, h3, l3;
    split_bf16(v.x, h0, l0); split_bf16(v.y, h1, l1);
    split_bf16(v.z, h2, l2); split_bf16(v.w, h3, l3);
    *(ushort4*)&xh[(size_t)i * 4] = make_ushort4(h0, h1, h2, h3);
    *(ushort4*)&xl[(size_t)i * 4] = make_ushort4(l0, l1, l2, l3);
  }
  if (gtid < 65536) {
    const float* Ws[3] = {Wq, Wk, Wv};
#pragma unroll
    for (int z = 0; z < 3; ++z) {
      float4 v = ((const float4*)Ws[z])[gtid];
      unsigned short h0, l0, h1, l1, h2, l2, h3, l3;
      split_bf16(v.x, h0, l0); split_bf16(v.y, h1, l1);
      split_bf16(v.z, h2, l2); split_bf16(v.w, h3, l3);
      size_t o = (size_t)z * 262144 + (size_t)gtid * 4;
      *(ushort4*)&wh[o] = make_ushort4(h0, h1, h2, h3);
      *(ushort4*)&wl[o] = make_ushort4(l0, l1, l2, l3);
    }
  }
}

// ---------------- Kernel 1: QKV projection (LDS-free, reg-prefetched) ----------------
#define PROJ_LOAD(K0, AH, AL, BH, BL)                                   \
  do {                                                                  \
    _Pragma("unroll") for (int t = 0; t < 2; ++t) {                     \
      size_t ao = abase + (size_t)t * 16 * 512 + (K0);                  \
      AH[t] = *(const short8*)(xh + ao);                                \
      AL[t] = *(const short8*)(xl + ao);                                \
    }                                                                   \
    _Pragma("unroll") for (int z = 0; z < 3; ++z)                       \
      _Pragma("unroll") for (int t = 0; t < 2; ++t) {                   \
        size_t bo = (size_t)z * 262144 + bbase + (size_t)t * 16 * 512 + (K0); \
        BH[z][t] = *(const short8*)(wh + bo);                           \
        BL[z][t] = *(const short8*)(wl + bo);                           \
      }                                                                 \
  } while (0)

#define PROJ_MFMA(AH, AL, BH, BL)                                       \
  do {                                                                  \
    _Pragma("unroll") for (int z = 0; z < 3; ++z)                       \
      _Pragma("unroll") for (int tm = 0; tm < 2; ++tm)                  \
        _Pragma("unroll") for (int tn = 0; tn < 2; ++tn) {              \
          acc[z][tm][tn] = MFMA16(AH[tm], BH[z][tn], acc[z][tm][tn]);   \
          acc[z][tm][tn] = MFMA16(AH[tm], BL[z][tn], acc[z][tm][tn]);   \
          acc[z][tm][tn] = MFMA16(AL[tm], BH[z][tn], acc[z][tm][tn]);   \
        }                                                               \
  } while (0)

__global__ __launch_bounds__(256, 2) void proj_kernel(
    const unsigned short* __restrict__ xh, const unsigned short* __restrict__ xl,
    const unsigned short* __restrict__ wh, const unsigned short* __restrict__ wl,
    unsigned short* __restrict__ Qh, unsigned short* __restrict__ Ql,
    unsigned short* __restrict__ Kh, unsigned short* __restrict__ Kl,
    unsigned short* __restrict__ Vh) {
  const int tid = threadIdx.x;
  const int w = tid >> 6, l = tid & 63;
  const int m0 = blockIdx.x * 64;
  const int h = blockIdx.y;
  const int lrow = l & 15, lg = l >> 4;
  const int rw = (w >> 1) * 32, cw = (w & 1) * 32;

  __shared__ __align__(16) unsigned short ob[2][64][72];  // 18.4 KB bounce

  f32x4 acc[3][2][2] = {};

  const size_t abase = (size_t)(m0 + rw + lrow) * 512 + lg * 8;
  const size_t bbase = (size_t)(h * 64 + cw + lrow) * 512 + lg * 8;

  short8 ah0[2], al0[2], bh0[3][2], bl0[3][2];
  short8 ah1[2], al1[2], bh1[3][2], bl1[3][2];

  PROJ_LOAD(0, ah0, al0, bh0, bl0);
#pragma unroll
  for (int k0 = 0; k0 < 512; k0 += 64) {
    PROJ_LOAD(k0 + 32, ah1, al1, bh1, bl1);
    PROJ_MFMA(ah0, al0, bh0, bl0);
    if (k0 + 64 < 512) PROJ_LOAD(k0 + 64, ah0, al0, bh0, bl0);
    PROJ_MFMA(ah1, al1, bh1, bl1);
  }

  // ---- epilogue: per-z bounce through LDS for coalesced stores ----
  const float qsc = 1.4426950408889634f * 0.08838834764831845f;  // log2e/sqrt(128)
  const int orow = tid >> 2, oc = (tid & 3) * 16;
  const int b = m0 >> 11, n0 = m0 & 2047, bhid = b * 8 + h;
#pragma unroll
  for (int z = 0; z < 3; ++z) {
    __syncthreads();
#pragma unroll
    for (int tm = 0; tm < 2; ++tm)
#pragma unroll
      for (int tn = 0; tn < 2; ++tn) {
        int dcol = cw + tn * 16 + lrow;
        int nl = rw + tm * 16 + lg * 4;
#pragma unroll
        for (int r = 0; r < 4; ++r) {
          float v = acc[z][tm][tn][r];
          if (z == 0) v *= qsc;
          unsigned short hi, lo;
          split_bf16(v, hi, lo);
          if (z < 2) {
            ob[0][nl + r][dcol] = hi;
            ob[1][nl + r][dcol] = lo;
          } else {
            ob[0][dcol][nl + r] = hi;  // transposed for V
          }
        }
      }
    __syncthreads();
    if (z < 2) {
      unsigned short* OH = (z == 0) ? Qh : Kh;
      unsigned short* OL = (z == 0) ? Ql : Kl;
      size_t base = ((size_t)bhid * 2048 + n0 + orow) * 64 + oc;
      *(short8*)&OH[base] = *(const short8*)&ob[0][orow][oc];
      *(short8*)&OH[base + 8] = *(const short8*)&ob[0][orow][oc + 8];
      *(short8*)&OL[base] = *(const short8*)&ob[1][orow][oc];
      *(short8*)&OL[base + 8] = *(const short8*)&ob[1][orow][oc + 8];
    } else {
      size_t vb = ((size_t)bhid * 64 + orow) * 2048 + n0 + oc;
      *(short8*)&Vh[vb] = *(const short8*)&ob[0][orow][oc];
      *(short8*)&Vh[vb + 8] = *(const short8*)&ob[0][orow][oc + 8];
    }
  }
}

// ---------------- attention body (R10 verbatim) ----------------
template <bool S2>
__device__ __forceinline__ void attn_body(
    unsigned short (&kvb)[2][3][64][64],
    const unsigned short* __restrict__ Qh, const unsigned short* __restrict__ Ql,
    const unsigned short* __restrict__ Kh, const unsigned short* __restrict__ Kl,
    const unsigned short* __restrict__ Vh,
    const unsigned long long* __restrict__ Mp, float* __restrict__ out) {
  const int tid = threadIdx.x;
  const int w = tid >> 6, l = tid & 63;
  const int wl = blockIdx.x;
  const int rm = (wl & 7) * 64 + (wl >> 3);  // XCD swizzle (512 = 8*64, bijective)
  const int q0 = (rm & 15) * 128;
  const int bh = rm >> 4;
  const int b = bh >> 3, h = bh & 7;
  const int l31 = l & 31, hi = l >> 5;
  const int swz = (l31 & 7) << 4;

  const unsigned short* Qhb = Qh + (size_t)bh * NSEQ * DH;
  const unsigned short* Qlb = Ql + (size_t)bh * NSEQ * DH;
  const unsigned short* Khb = Kh + (size_t)bh * NSEQ * DH;
  const unsigned short* Klb = Kl + (size_t)bh * NSEQ * DH;
  const unsigned short* Vhb = Vh + (size_t)bh * DH * NSEQ;
  const unsigned long long* Mb = Mp + (size_t)b * NSEQ * 32;
  float* Ob = out + (size_t)b * NSEQ * 512 + h * 64;

  char* kv0 = (char*)&kvb[0][0][0][0];  // buf stride 24576: Kh / +8192 Kl / +16384 Vh

  int va[4];
#pragma unroll
  for (int d = 0; d < 4; ++d) va[d] = l31 * 128 + (((d * 32) | (hi * 16)) ^ swz);

  const size_t qoff = (size_t)(q0 + w * 32 + l31) * 64 + hi * 8;
  short8 qh[4], ql[4];
#pragma unroll
  for (int d = 0; d < 4; ++d) {
    qh[d] = *(const short8*)(Qhb + qoff + d * 16);
    ql[d] = *(const short8*)(Qlb + qoff + d * 16);
  }

  f32x16 o[2] = {};
  float mrun = -1e30f, lrun = 0.0f;
  const int qglob = q0 + w * 32 + l31;

  const int r0 = tid >> 3, ch0 = (tid & 7) * 8;
  const int r1 = (tid + 256) >> 3, ch1 = ((tid + 256) & 7) * 8;
  const int dst0 = r0 * 128 + ((ch0 * 2) ^ ((r0 & 7) << 4));
  const int dst1 = r1 * 128 + ((ch1 * 2) ^ ((r1 & 7) << 4));
  size_t ka = (size_t)r0 * 64 + ch0, kb = (size_t)r1 * 64 + ch1;
  size_t vao = (size_t)r0 * 2048 + ch0, vbo = (size_t)r1 * 2048 + ch1;

  short8 sKh0 = *(const short8*)(Khb + ka), sKh1 = *(const short8*)(Khb + kb);
  short8 sKl0 = *(const short8*)(Klb + ka), sKl1 = *(const short8*)(Klb + kb);
  short8 sVh0 = *(const short8*)(Vhb + vao), sVh1 = *(const short8*)(Vhb + vbo);
  {
    char* nb = kv0;
    *(short8*)(nb + dst0) = sKh0;          *(short8*)(nb + dst1) = sKh1;
    *(short8*)(nb + dst0 + 8192) = sKl0;   *(short8*)(nb + dst1 + 8192) = sKl1;
    *(short8*)(nb + dst0 + 16384) = sVh0;  *(short8*)(nb + dst1 + 16384) = sVh1;
  }
  ka += 4096; kb += 4096; vao += 64; vbo += 64;
  sKh0 = *(const short8*)(Khb + ka); sKh1 = *(const short8*)(Khb + kb);
  sKl0 = *(const short8*)(Klb + ka); sKl1 = *(const short8*)(Klb + kb);
  sVh0 = *(const short8*)(Vhb + vao); sVh1 = *(const short8*)(Vhb + vbo);
  __syncthreads();

  for (int it = 0; it < 32; ++it) {
    char* cur = kv0 + (size_t)(it & 1) * 24576;
    if (it < 31) {
      char* nb = kv0 + (size_t)((it + 1) & 1) * 24576;
      *(short8*)(nb + dst0) = sKh0;          *(short8*)(nb + dst1) = sKh1;
      *(short8*)(nb + dst0 + 8192) = sKl0;   *(short8*)(nb + dst1 + 8192) = sKl1;
      *(short8*)(nb + dst0 + 16384) = sVh0;  *(short8*)(nb + dst1 + 16384) = sVh1;
      if (it < 30) {
        ka += 4096; kb += 4096; vao += 64; vbo += 64;
        sKh0 = *(const short8*)(Khb + ka); sKh1 = *(const short8*)(Khb + kb);
        sKl0 = *(const short8*)(Klb + ka); sKl1 = *(const short8*)(Klb + kb);
        sVh0 = *(const short8*)(Vhb + vao); sVh1 = *(const short8*)(Vhb + vbo);
      }
    }

    // ---- S^T = K Q^T (split-bf16, 3 MFMAs) ----
    f32x16 s[2] = {};
    __builtin_amdgcn_s_setprio(1);
#pragma unroll
    for (int d = 0; d < 4; ++d) {
#pragma unroll
      for (int kt = 0; kt < 2; ++kt) {
        short8 kfh = *(const short8*)(cur + kt * 4096 + va[d]);
        short8 kfl = *(const short8*)(cur + 8192 + kt * 4096 + va[d]);
        s[kt] = MFMA32(kfh, qh[d], s[kt]);
        s[kt] = MFMA32(kfh, ql[d], s[kt]);
        s[kt] = MFMA32(kfl, qh[d], s[kt]);
      }
    }
    __builtin_amdgcn_s_setprio(0);

    // ---- mask ----
    const unsigned long long mw = Mb[(size_t)qglob * 32 + it];
#pragma unroll
    for (int kt = 0; kt < 2; ++kt)
#pragma unroll
      for (int m = 0; m < 4; ++m) {
        unsigned nib = ((unsigned)(mw >> (kt * 32 + m * 8 + 4 * hi))) & 0xFu;
#pragma unroll
        for (int r = 0; r < 4; ++r)
          s[kt][4 * m + r] = ((nib >> r) & 1u) ? -1e30f : s[kt][4 * m + r];
      }

    // ---- lane-local online softmax (exp2 domain) ----
    float mx = s[0][0];
#pragma unroll
    for (int kt = 0; kt < 2; ++kt)
#pragma unroll
      for (int e = 0; e < 16; ++e) mx = fmaxf(mx, s[kt][e]);
    mx = fmaxf(mx, __shfl_xor(mx, 32));
    const bool grow = __any(mx > mrun + 11.0f);
    const float mnew = grow ? fmaxf(mrun, mx) : mrun;

    float rs = 0.0f;
#pragma unroll
    for (int kt = 0; kt < 2; ++kt)
#pragma unroll
      for (int e = 0; e < 16; ++e) {
        float p = EXP2(s[kt][e] - mnew);
        s[kt][e] = p;
        rs += p;
      }
    rs += __shfl_xor(rs, 32);
    if (grow) {
      float sc = EXP2(mrun - mnew);
      lrun = lrun * sc + rs;
      mrun = mnew;
#pragma unroll
      for (int dt = 0; dt < 2; ++dt)
#pragma unroll
        for (int e = 0; e < 16; ++e) o[dt][e] *= sc;
    } else {
      lrun += rs;
    }

    // ---- P -> PV B-frags in-register (single bf16) ----
    short8 fragh[4];
#pragma unroll
    for (int kt = 0; kt < 2; ++kt) {
      unsigned c0h[4], c1h[4];
#pragma unroll
      for (int m = 0; m < 4; ++m) {
        c0h[m] = cvtpk_bf16(s[kt][4 * m + 0], s[kt][4 * m + 1]);
        c1h[m] = cvtpk_bf16(s[kt][4 * m + 2], s[kt][4 * m + 3]);
      }
#pragma unroll
      for (int sI = 0; sI < 2; ++sI) {
        unsigned dw0, dw1, dw2, dw3;
        xsw<S2>(c0h[2 * sI], c0h[2 * sI + 1], dw0, dw2);
        xsw<S2>(c1h[2 * sI], c1h[2 * sI + 1], dw1, dw3);
        union U { uint4 u; short8 s8; } FH;
        FH.u = make_uint4(dw0, dw1, dw2, dw3);
        fragh[kt * 2 + sI] = FH.s8;
      }
    }

    // ---- O += V^T P (single bf16 V) ----
    __builtin_amdgcn_s_setprio(1);
#pragma unroll
    for (int dt = 0; dt < 2; ++dt) {
#pragma unroll
      for (int ks = 0; ks < 4; ++ks) {
        short8 vfh = *(const short8*)(cur + 16384 + dt * 4096 + va[ks]);
        o[dt] = MFMA32(vfh, fragh[ks], o[dt]);
      }
    }
    __builtin_amdgcn_s_setprio(0);

    __syncthreads();
  }

  // ---- epilogue ----
  const float invl = lrun > 0.0f ? 1.0f / lrun : 0.0f;
#pragma unroll
  for (int dt = 0; dt < 2; ++dt)
#pragma unroll
    for (int m = 0; m < 4; ++m) {
      float4 v;
      v.x = o[dt][4 * m + 0] * invl;
      v.y = o[dt][4 * m + 1] * invl;
      v.z = o[dt][4 * m + 2] * invl;
      v.w = o[dt][4 * m + 3] * invl;
      const int d = dt * 32 + m * 8 + 4 * hi;
      *(float4*)&Ob[(size_t)qglob * 512 + d] = v;
    }
}

// ---------------- Kernel 2: flash attention ----------------
__global__ __launch_bounds__(256, 2) void attn_kernel(
    const unsigned short* __restrict__ Qh, const unsigned short* __restrict__ Ql,
    const unsigned short* __restrict__ Kh, const unsigned short* __restrict__ Kl,
    const unsigned short* __restrict__ Vh,
    const unsigned long long* __restrict__ Mp, float* __restrict__ out) {
  __shared__ __align__(16) unsigned short kvb[2][3][64][64];  // 48 KB double buffer

  const int hi = (threadIdx.x & 63) >> 5;
  unsigned ta = 1u + (unsigned)hi;
  unsigned tb = 3u + (unsigned)hi;
  permswap(ta, tb);
  const bool s2 = (__builtin_amdgcn_readfirstlane(ta) == 1u);

  if (s2) attn_body<true>(kvb, Qh, Ql, Kh, Kl, Vh, Mp, out);
  else    attn_body<false>(kvb, Qh, Ql, Kh, Kl, Vh, Mp, out);
}

extern "C" void kernel_launch(void* const* d_in, const int* in_sizes, int n_in,
                              void* d_out, int out_size, void* d_ws, size_t ws_size,
                              hipStream_t stream) {
  const float* x = (const float*)d_in[0];
  const void* mask = d_in[1];
  const float* Wq = (const float*)d_in[2];
  const float* Wk = (const float*)d_in[3];
  const float* Wv = (const float*)d_in[4];
  float* out = (float*)d_out;

  const size_t PLANE = (size_t)NBH * NSEQ * DH;  // 4,194,304 ushorts (= x elems)
  unsigned short* Qh = (unsigned short*)d_ws;
  unsigned short* Ql = Qh + PLANE;
  unsigned short* Kh = Ql + PLANE;
  unsigned short* Kl = Kh + PLANE;
  unsigned short* Vh = Kl + PLANE;
  unsigned short* xh = Vh + PLANE;
  unsigned short* xl = xh + PLANE;
  unsigned short* wh = xl + PLANE;               // 3 * 262,144 ushorts
  unsigned short* wl = wh + 786432;
  unsigned long long* Mp = (unsigned long long*)(wl + 786432);  // 2 MB

  prep_kernel<<<1024, 256, 0, stream>>>(mask, Mp, x, Wq, Wk, Wv, xh, xl, wh, wl);
  proj_kernel<<<dim3(128, 8), 256, 0, stream>>>(xh, xl, wh, wl, Qh, Ql, Kh, Kl, Vh);
  attn_kernel<<<512, 256, 0, stream>>>(Qh, Ql, Kh, Kl, Vh, Mp, out);
}

// Round 12
// 151.452 us; speedup vs baseline: 1.4756x; 1.4756x over previous
//
#include <hip/hip_runtime.h>

// Attention_29231547416680: B=4, N=2048, CH=512, H=8, D=64, fp32 in/out.
// R12 = R11 with proj rebuilt on global_load_lds (m97 structure): async DMA
//       staging of pre-split planes into 32KB LDS tiles, 2-barrier K-loop,
//       4 blocks/CU. attn (single-bf16 PV) and prep unchanged from R11.

typedef float f32x4 __attribute__((ext_vector_type(4)));
typedef float f32x16 __attribute__((ext_vector_type(16)));
typedef short short8 __attribute__((ext_vector_type(8)));

#define MFMA16(a, b, c) __builtin_amdgcn_mfma_f32_16x16x32_bf16((a), (b), (c), 0, 0, 0)
#define MFMA32(a, b, c) __builtin_amdgcn_mfma_f32_32x32x16_bf16((a), (b), (c), 0, 0, 0)

#if __has_builtin(__builtin_amdgcn_exp2f)
#define EXP2(x) __builtin_amdgcn_exp2f(x)
#else
#define EXP2(x) exp2f(x)
#endif

#define NBH 32
#define NSEQ 2048
#define DH 64

__device__ __forceinline__ unsigned short f2bf(float f) {
  unsigned int u = __float_as_uint(f);
  u += 0x7fffu + ((u >> 16) & 1u);  // RTNE
  return (unsigned short)(u >> 16);
}
__device__ __forceinline__ float bf2f(unsigned short h) {
  return __uint_as_float(((unsigned int)h) << 16);
}
__device__ __forceinline__ void split_bf16(float f, unsigned short& hi, unsigned short& lo) {
  hi = f2bf(f);
  lo = f2bf(f - bf2f(hi));
}

__device__ __forceinline__ unsigned cvtpk_bf16(float a, float b) {
  unsigned d;
  asm("v_cvt_pk_bf16_f32 %0, %1, %2" : "=v"(d) : "v"(a), "v"(b));
  return d;
}
__device__ __forceinline__ void permswap(unsigned& a, unsigned& b) {
  asm("v_permlane32_swap_b32 %0, %1" : "+v"(a), "+v"(b));
}
// lo = (ce.row0 | co.row0), hi = (ce.row1 | co.row1); S2 selects HW direction.
template <bool S2>
__device__ __forceinline__ void xsw(unsigned ce, unsigned co, unsigned& lo, unsigned& hi) {
  if (S2) { permswap(ce, co); }
  else    { permswap(co, ce); }
  lo = ce;
  hi = co;
}

// async global -> LDS, 16 bytes per lane; LDS dst = wave-uniform base + lane*16.
typedef __attribute__((address_space(1))) const unsigned int as1_u32;
typedef __attribute__((address_space(3))) unsigned int as3_u32;
__device__ __forceinline__ void gld_lds16(const unsigned short* g, unsigned short* l) {
  __builtin_amdgcn_global_load_lds((as1_u32*)g, (as3_u32*)l, 16, 0, 0);
}

// ---------------- prep: mask bit-pack + x/W hi-lo split (R11 verbatim) ----------------
__global__ __launch_bounds__(256) void prep_kernel(
    const void* __restrict__ mraw, unsigned long long* __restrict__ Mp,
    const float* __restrict__ x,
    const float* __restrict__ Wq, const float* __restrict__ Wk, const float* __restrict__ Wv,
    unsigned short* __restrict__ xh, unsigned short* __restrict__ xl,
    unsigned short* __restrict__ wh, unsigned short* __restrict__ wl) {
  const int tid = threadIdx.x;
  __shared__ int s_bad;
  if (tid == 0) s_bad = 0;
  __syncthreads();
  const unsigned int* mw32 = (const unsigned int*)mraw;
  {
    unsigned int w0 = mw32[tid], w1 = mw32[256 + tid];
    bool ok = (w0 == 0u || w0 == 1u || w0 == 0x3f800000u) &&
              (w1 == 0u || w1 == 1u || w1 == 0x3f800000u);
    if (!ok) s_bad = 1;
  }
  __syncthreads();
  const size_t e0 = (size_t)blockIdx.x * 16384 + (size_t)tid * 64;
  unsigned long long bits = 0ull;
  if (s_bad == 0) {
    const uint4* p = (const uint4*)mw32 + (e0 >> 2);
#pragma unroll
    for (int j = 0; j < 16; ++j) {
      uint4 v = p[j];
      unsigned nib = (v.x != 0u) | ((v.y != 0u) << 1) | ((v.z != 0u) << 2) | ((v.w != 0u) << 3);
      bits |= (unsigned long long)nib << (j * 4);
    }
  } else {
    const uint4* p = (const uint4*)((const unsigned char*)mraw + e0);
#pragma unroll
    for (int j = 0; j < 4; ++j) {
      uint4 v = p[j];
      unsigned dw[4] = {v.x, v.y, v.z, v.w};
#pragma unroll
      for (int d = 0; d < 4; ++d) {
        unsigned nib = (((dw[d]) & 0xffu) != 0u) | ((((dw[d] >> 8) & 0xffu) != 0u) << 1) |
                       ((((dw[d] >> 16) & 0xffu) != 0u) << 2) | ((((dw[d] >> 24) & 0xffu) != 0u) << 3);
        bits |= (unsigned long long)nib << ((j * 4 + d) * 4);
      }
    }
  }
  Mp[e0 >> 6] = bits;

  const int gtid = blockIdx.x * 256 + tid;
  const float4* x4 = (const float4*)x;
#pragma unroll
  for (int rep = 0; rep < 4; ++rep) {
    int i = gtid + rep * 262144;
    float4 v = x4[i];
    unsigned short h0, l0, h1, l1, h2, l2, h3, l3;
    split_bf16(v.x, h0, l0); split_bf16(v.y, h1, l1);
    split_bf16(v.z, h2, l2); split_bf16(v.w, h3, l3);
    *(ushort4*)&xh[(size_t)i * 4] = make_ushort4(h0, h1, h2, h3);
    *(ushort4*)&xl[(size_t)i * 4] = make_ushort4(l0, l1, l2, l3);
  }
  if (gtid < 65536) {
    const float* Ws[3] = {Wq, Wk, Wv};
#pragma unroll
    for (int z = 0; z < 3; ++z) {
      float4 v = ((const float4*)Ws[z])[gtid];
      unsigned short h0, l0, h1, l1, h2, l2, h3, l3;
      split_bf16(v.x, h0, l0); split_bf16(v.y, h1, l1);
      split_bf16(v.z, h2, l2); split_bf16(v.w, h3, l3);
      size_t o = (size_t)z * 262144 + (size_t)gtid * 4;
      *(ushort4*)&wh[o] = make_ushort4(h0, h1, h2, h3);
      *(ushort4*)&wl[o] = make_ushort4(l0, l1, l2, l3);
    }
  }
}

// ---------------- Kernel 1: QKV projection (global_load_lds staged) ----------------
// Tiles (each [64][32] ushort, 4KB): 0 Axh, 1 Axl, 2+2z Bzh, 3+2z Bzl. 32KB/step.
__global__ __launch_bounds__(256, 4) void proj_kernel(
    const unsigned short* __restrict__ xh, const unsigned short* __restrict__ xl,
    const unsigned short* __restrict__ wh, const unsigned short* __restrict__ wl,
    unsigned short* __restrict__ Qh, unsigned short* __restrict__ Ql,
    unsigned short* __restrict__ Kh, unsigned short* __restrict__ Kl,
    unsigned short* __restrict__ Vh) {
  const int tid = threadIdx.x;
  const int w = tid >> 6, l = tid & 63;
  const int m0 = blockIdx.x * 64;
  const int h = blockIdx.y;
  const int lrow = l & 15, lg = l >> 4;
  const int rw = (w >> 1) * 32, cw = (w & 1) * 32;

  union LDSU {
    unsigned short tiles[8][64][32];  // 32 KB staging
    unsigned short ob[2][64][72];     // 18.4 KB epilogue bounce
  };
  __shared__ __align__(16) LDSU u;

  f32x4 acc[3][2][2] = {};

  // wave w stages tiles 2w and 2w+1 (4 gld_lds16 calls each per step)
  const unsigned short* planes[8] = {xh, xl, wh, wl, wh + 262144, wl + 262144,
                                     wh + 524288, wl + 524288};
  const int rowb[8] = {m0, m0, h * 64, h * 64, h * 64, h * 64, h * 64, h * 64};
  const int srow = l >> 2, scol = (l & 3) * 8;  // lane -> (row within 16, col chunk)
  const unsigned short* s0 = planes[2 * w] + (size_t)(rowb[2 * w] + srow) * 512 + scol;
  const unsigned short* s1 = planes[2 * w + 1] + (size_t)(rowb[2 * w + 1] + srow) * 512 + scol;
  unsigned short* d0 = &u.tiles[2 * w][0][0];
  unsigned short* d1 = &u.tiles[2 * w + 1][0][0];

  for (int k0 = 0; k0 < 512; k0 += 32) {
    __syncthreads();  // previous step's reads done; tiles reusable
#pragma unroll
    for (int c = 0; c < 4; ++c) {
      gld_lds16(s0 + k0 + c * 8192, d0 + c * 512);  // 16 rows per call
      gld_lds16(s1 + k0 + c * 8192, d1 + c * 512);
    }
    __syncthreads();  // compiler drains vmcnt before barrier

    short8 axh[2], axl[2];
#pragma unroll
    for (int t = 0; t < 2; ++t) {
      axh[t] = *(const short8*)&u.tiles[0][rw + 16 * t + lrow][lg * 8];
      axl[t] = *(const short8*)&u.tiles[1][rw + 16 * t + lrow][lg * 8];
    }
#pragma unroll
    for (int z = 0; z < 3; ++z) {
      short8 bh[2], bl[2];
#pragma unroll
      for (int t = 0; t < 2; ++t) {
        bh[t] = *(const short8*)&u.tiles[2 + 2 * z][cw + 16 * t + lrow][lg * 8];
        bl[t] = *(const short8*)&u.tiles[3 + 2 * z][cw + 16 * t + lrow][lg * 8];
      }
#pragma unroll
      for (int tm = 0; tm < 2; ++tm)
#pragma unroll
        for (int tn = 0; tn < 2; ++tn) {
          acc[z][tm][tn] = MFMA16(axh[tm], bh[tn], acc[z][tm][tn]);
          acc[z][tm][tn] = MFMA16(axh[tm], bl[tn], acc[z][tm][tn]);
          acc[z][tm][tn] = MFMA16(axl[tm], bh[tn], acc[z][tm][tn]);
        }
    }
  }

  // ---- epilogue: per-z bounce through LDS for coalesced stores ----
  const float qsc = 1.4426950408889634f * 0.08838834764831845f;  // log2e/sqrt(128)
  const int orow = tid >> 2, oc = (tid & 3) * 16;
  const int b = m0 >> 11, n0 = m0 & 2047, bhid = b * 8 + h;
#pragma unroll
  for (int z = 0; z < 3; ++z) {
    __syncthreads();
#pragma unroll
    for (int tm = 0; tm < 2; ++tm)
#pragma unroll
      for (int tn = 0; tn < 2; ++tn) {
        int dcol = cw + tn * 16 + lrow;
        int nl = rw + tm * 16 + lg * 4;
#pragma unroll
        for (int r = 0; r < 4; ++r) {
          float v = acc[z][tm][tn][r];
          if (z == 0) v *= qsc;
          unsigned short hi, lo;
          split_bf16(v, hi, lo);
          if (z < 2) {
            u.ob[0][nl + r][dcol] = hi;
            u.ob[1][nl + r][dcol] = lo;
          } else {
            u.ob[0][dcol][nl + r] = hi;  // transposed for V
          }
        }
      }
    __syncthreads();
    if (z < 2) {
      unsigned short* OH = (z == 0) ? Qh : Kh;
      unsigned short* OL = (z == 0) ? Ql : Kl;
      size_t base = ((size_t)bhid * 2048 + n0 + orow) * 64 + oc;
      *(short8*)&OH[base] = *(const short8*)&u.ob[0][orow][oc];
      *(short8*)&OH[base + 8] = *(const short8*)&u.ob[0][orow][oc + 8];
      *(short8*)&OL[base] = *(const short8*)&u.ob[1][orow][oc];
      *(short8*)&OL[base + 8] = *(const short8*)&u.ob[1][orow][oc + 8];
    } else {
      size_t vb = ((size_t)bhid * 64 + orow) * 2048 + n0 + oc;
      *(short8*)&Vh[vb] = *(const short8*)&u.ob[0][orow][oc];
      *(short8*)&Vh[vb + 8] = *(const short8*)&u.ob[0][orow][oc + 8];
    }
  }
}

// ---------------- attention body (R11 verbatim) ----------------
template <bool S2>
__device__ __forceinline__ void attn_body(
    unsigned short (&kvb)[2][3][64][64],
    const unsigned short* __restrict__ Qh, const unsigned short* __restrict__ Ql,
    const unsigned short* __restrict__ Kh, const unsigned short* __restrict__ Kl,
    const unsigned short* __restrict__ Vh,
    const unsigned long long* __restrict__ Mp, float* __restrict__ out) {
  const int tid = threadIdx.x;
  const int w = tid >> 6, l = tid & 63;
  const int wl = blockIdx.x;
  const int rm = (wl & 7) * 64 + (wl >> 3);  // XCD swizzle (512 = 8*64, bijective)
  const int q0 = (rm & 15) * 128;
  const int bh = rm >> 4;
  const int b = bh >> 3, h = bh & 7;
  const int l31 = l & 31, hi = l >> 5;
  const int swz = (l31 & 7) << 4;

  const unsigned short* Qhb = Qh + (size_t)bh * NSEQ * DH;
  const unsigned short* Qlb = Ql + (size_t)bh * NSEQ * DH;
  const unsigned short* Khb = Kh + (size_t)bh * NSEQ * DH;
  const unsigned short* Klb = Kl + (size_t)bh * NSEQ * DH;
  const unsigned short* Vhb = Vh + (size_t)bh * DH * NSEQ;
  const unsigned long long* Mb = Mp + (size_t)b * NSEQ * 32;
  float* Ob = out + (size_t)b * NSEQ * 512 + h * 64;

  char* kv0 = (char*)&kvb[0][0][0][0];  // buf stride 24576: Kh / +8192 Kl / +16384 Vh

  int va[4];
#pragma unroll
  for (int d = 0; d < 4; ++d) va[d] = l31 * 128 + (((d * 32) | (hi * 16)) ^ swz);

  const size_t qoff = (size_t)(q0 + w * 32 + l31) * 64 + hi * 8;
  short8 qh[4], ql[4];
#pragma unroll
  for (int d = 0; d < 4; ++d) {
    qh[d] = *(const short8*)(Qhb + qoff + d * 16);
    ql[d] = *(const short8*)(Qlb + qoff + d * 16);
  }

  f32x16 o[2] = {};
  float mrun = -1e30f, lrun = 0.0f;
  const int qglob = q0 + w * 32 + l31;

  const int r0 = tid >> 3, ch0 = (tid & 7) * 8;
  const int r1 = (tid + 256) >> 3, ch1 = ((tid + 256) & 7) * 8;
  const int dst0 = r0 * 128 + ((ch0 * 2) ^ ((r0 & 7) << 4));
  const int dst1 = r1 * 128 + ((ch1 * 2) ^ ((r1 & 7) << 4));
  size_t ka = (size_t)r0 * 64 + ch0, kb = (size_t)r1 * 64 + ch1;
  size_t vao = (size_t)r0 * 2048 + ch0, vbo = (size_t)r1 * 2048 + ch1;

  short8 sKh0 = *(const short8*)(Khb + ka), sKh1 = *(const short8*)(Khb + kb);
  short8 sKl0 = *(const short8*)(Klb + ka), sKl1 = *(const short8*)(Klb + kb);
  short8 sVh0 = *(const short8*)(Vhb + vao), sVh1 = *(const short8*)(Vhb + vbo);
  {
    char* nb = kv0;
    *(short8*)(nb + dst0) = sKh0;          *(short8*)(nb + dst1) = sKh1;
    *(short8*)(nb + dst0 + 8192) = sKl0;   *(short8*)(nb + dst1 + 8192) = sKl1;
    *(short8*)(nb + dst0 + 16384) = sVh0;  *(short8*)(nb + dst1 + 16384) = sVh1;
  }
  ka += 4096; kb += 4096; vao += 64; vbo += 64;
  sKh0 = *(const short8*)(Khb + ka); sKh1 = *(const short8*)(Khb + kb);
  sKl0 = *(const short8*)(Klb + ka); sKl1 = *(const short8*)(Klb + kb);
  sVh0 = *(const short8*)(Vhb + vao); sVh1 = *(const short8*)(Vhb + vbo);
  __syncthreads();

  for (int it = 0; it < 32; ++it) {
    char* cur = kv0 + (size_t)(it & 1) * 24576;
    if (it < 31) {
      char* nb = kv0 + (size_t)((it + 1) & 1) * 24576;
      *(short8*)(nb + dst0) = sKh0;          *(short8*)(nb + dst1) = sKh1;
      *(short8*)(nb + dst0 + 8192) = sKl0;   *(short8*)(nb + dst1 + 8192) = sKl1;
      *(short8*)(nb + dst0 + 16384) = sVh0;  *(short8*)(nb + dst1 + 16384) = sVh1;
      if (it < 30) {
        ka += 4096; kb += 4096; vao += 64; vbo += 64;
        sKh0 = *(const short8*)(Khb + ka); sKh1 = *(const short8*)(Khb + kb);
        sKl0 = *(const short8*)(Klb + ka); sKl1 = *(const short8*)(Klb + kb);
        sVh0 = *(const short8*)(Vhb + vao); sVh1 = *(const short8*)(Vhb + vbo);
      }
    }

    // ---- S^T = K Q^T (split-bf16, 3 MFMAs) ----
    f32x16 s[2] = {};
    __builtin_amdgcn_s_setprio(1);
#pragma unroll
    for (int d = 0; d < 4; ++d) {
#pragma unroll
      for (int kt = 0; kt < 2; ++kt) {
        short8 kfh = *(const short8*)(cur + kt * 4096 + va[d]);
        short8 kfl = *(const short8*)(cur + 8192 + kt * 4096 + va[d]);
        s[kt] = MFMA32(kfh, qh[d], s[kt]);
        s[kt] = MFMA32(kfh, ql[d], s[kt]);
        s[kt] = MFMA32(kfl, qh[d], s[kt]);
      }
    }
    __builtin_amdgcn_s_setprio(0);

    // ---- mask ----
    const unsigned long long mw = Mb[(size_t)qglob * 32 + it];
#pragma unroll
    for (int kt = 0; kt < 2; ++kt)
#pragma unroll
      for (int m = 0; m < 4; ++m) {
        unsigned nib = ((unsigned)(mw >> (kt * 32 + m * 8 + 4 * hi))) & 0xFu;
#pragma unroll
        for (int r = 0; r < 4; ++r)
          s[kt][4 * m + r] = ((nib >> r) & 1u) ? -1e30f : s[kt][4 * m + r];
      }

    // ---- lane-local online softmax (exp2 domain) ----
    float mx = s[0][0];
#pragma unroll
    for (int kt = 0; kt < 2; ++kt)
#pragma unroll
      for (int e = 0; e < 16; ++e) mx = fmaxf(mx, s[kt][e]);
    mx = fmaxf(mx, __shfl_xor(mx, 32));
    const bool grow = __any(mx > mrun + 11.0f);
    const float mnew = grow ? fmaxf(mrun, mx) : mrun;

    float rs = 0.0f;
#pragma unroll
    for (int kt = 0; kt < 2; ++kt)
#pragma unroll
      for (int e = 0; e < 16; ++e) {
        float p = EXP2(s[kt][e] - mnew);
        s[kt][e] = p;
        rs += p;
      }
    rs += __shfl_xor(rs, 32);
    if (grow) {
      float sc = EXP2(mrun - mnew);
      lrun = lrun * sc + rs;
      mrun = mnew;
#pragma unroll
      for (int dt = 0; dt < 2; ++dt)
#pragma unroll
        for (int e = 0; e < 16; ++e) o[dt][e] *= sc;
    } else {
      lrun += rs;
    }

    // ---- P -> PV B-frags in-register (single bf16) ----
    short8 fragh[4];
#pragma unroll
    for (int kt = 0; kt < 2; ++kt) {
      unsigned c0h[4], c1h[4];
#pragma unroll
      for (int m = 0; m < 4; ++m) {
        c0h[m] = cvtpk_bf16(s[kt][4 * m + 0], s[kt][4 * m + 1]);
        c1h[m] = cvtpk_bf16(s[kt][4 * m + 2], s[kt][4 * m + 3]);
      }
#pragma unroll
      for (int sI = 0; sI < 2; ++sI) {
        unsigned dw0, dw1, dw2, dw3;
        xsw<S2>(c0h[2 * sI], c0h[2 * sI + 1], dw0, dw2);
        xsw<S2>(c1h[2 * sI], c1h[2 * sI + 1], dw1, dw3);
        union U { uint4 u; short8 s8; } FH;
        FH.u = make_uint4(dw0, dw1, dw2, dw3);
        fragh[kt * 2 + sI] = FH.s8;
      }
    }

    // ---- O += V^T P (single bf16 V) ----
    __builtin_amdgcn_s_setprio(1);
#pragma unroll
    for (int dt = 0; dt < 2; ++dt) {
#pragma unroll
      for (int ks = 0; ks < 4; ++ks) {
        short8 vfh = *(const short8*)(cur + 16384 + dt * 4096 + va[ks]);
        o[dt] = MFMA32(vfh, fragh[ks], o[dt]);
      }
    }
    __builtin_amdgcn_s_setprio(0);

    __syncthreads();
  }

  // ---- epilogue ----
  const float invl = lrun > 0.0f ? 1.0f / lrun : 0.0f;
#pragma unroll
  for (int dt = 0; dt < 2; ++dt)
#pragma unroll
    for (int m = 0; m < 4; ++m) {
      float4 v;
      v.x = o[dt][4 * m + 0] * invl;
      v.y = o[dt][4 * m + 1] * invl;
      v.z = o[dt][4 * m + 2] * invl;
      v.w = o[dt][4 * m + 3] * invl;
      const int d = dt * 32 + m * 8 + 4 * hi;
      *(float4*)&Ob[(size_t)qglob * 512 + d] = v;
    }
}

// ---------------- Kernel 2: flash attention ----------------
__global__ __launch_bounds__(256, 2) void attn_kernel(
    const unsigned short* __restrict__ Qh, const unsigned short* __restrict__ Ql,
    const unsigned short* __restrict__ Kh, const unsigned short* __restrict__ Kl,
    const unsigned short* __restrict__ Vh,
    const unsigned long long* __restrict__ Mp, float* __restrict__ out) {
  __shared__ __align__(16) unsigned short kvb[2][3][64][64];  // 48 KB double buffer

  const int hi = (threadIdx.x & 63) >> 5;
  unsigned ta = 1u + (unsigned)hi;
  unsigned tb = 3u + (unsigned)hi;
  permswap(ta, tb);
  const bool s2 = (__builtin_amdgcn_readfirstlane(ta) == 1u);

  if (s2) attn_body<true>(kvb, Qh, Ql, Kh, Kl, Vh, Mp, out);
  else    attn_body<false>(kvb, Qh, Ql, Kh, Kl, Vh, Mp, out);
}

extern "C" void kernel_launch(void* const* d_in, const int* in_sizes, int n_in,
                              void* d_out, int out_size, void* d_ws, size_t ws_size,
                              hipStream_t stream) {
  const float* x = (const float*)d_in[0];
  const void* mask = d_in[1];
  const float* Wq = (const float*)d_in[2];
  const float* Wk = (const float*)d_in[3];
  const float* Wv = (const float*)d_in[4];
  float* out = (float*)d_out;

  const size_t PLANE = (size_t)NBH * NSEQ * DH;  // 4,194,304 ushorts (= x elems)
  unsigned short* Qh = (unsigned short*)d_ws;
  unsigned short* Ql = Qh + PLANE;
  unsigned short* Kh = Ql + PLANE;
  unsigned short* Kl = Kh + PLANE;
  unsigned short* Vh = Kl + PLANE;
  unsigned short* xh = Vh + PLANE;
  unsigned short* xl = xh + PLANE;
  unsigned short* wh = xl + PLANE;               // 3 * 262,144 ushorts
  unsigned short* wl = wh + 786432;
  unsigned long long* Mp = (unsigned long long*)(wl + 786432);  // 2 MB

  prep_kernel<<<1024, 256, 0, stream>>>(mask, Mp, x, Wq, Wk, Wv, xh, xl, wh, wl);
  proj_kernel<<<dim3(128, 8), 256, 0, stream>>>(xh, xl, wh, wl, Qh, Ql, Kh, Kl, Vh);
  attn_kernel<<<512, 256, 0, stream>>>(Qh, Ql, Kh, Kl, Vh, Mp, out);
}